// Round 20
// baseline (671.710 us; speedup 1.0000x reference)
//
#include <hip/hip_runtime.h>
#include <hip/hip_bf16.h>

#define N_NODES 100000
#define IN_F 128
#define OUT_F 64
#define BROWS 64                  // rows per bucket
#define NB 1563                   // ceil(100000/64)
#define BIN_TILE 4096             // edges per bin tile
#define NSEG 8                    // sub-cursors; g=blockIdx&7
#define SCAP 192                  // segment capacity (mean 128 + 5.7 sigma)
#define BCAP (NSEG * SCAP)        // 1536 per bucket
#define OVCAP 131072              // overflow list capacity
#define CSB_CAP BCAP              // LDS edge buffer

typedef __attribute__((ext_vector_type(8))) short bf16x8;
typedef __attribute__((ext_vector_type(4))) float f32x4;

// RNE float -> bf16 (bits)
__device__ __forceinline__ unsigned short f2bf(float x) {
    unsigned u = __float_as_uint(x);
    u += 0x7FFFu + ((u >> 16) & 1u);
    return (unsigned short)(u >> 16);
}
// bf16 (bits) -> float (exact)
__device__ __forceinline__ float bf2f(unsigned short s) {
    return __uint_as_float(((unsigned)s) << 16);
}

// ===========================================================================
// Kernel 0: Wt[c][k] = bf16(W[k][c])  (64 x 128 bf16, 16 KB, L2-hot after)
// ===========================================================================
__global__ __launch_bounds__(256) void wt_kernel(
    const float* __restrict__ W, unsigned short* __restrict__ Wt)
{
    int i = blockIdx.x * 256 + threadIdx.x;
    if (i < IN_F * OUT_F) {
        int c = i >> 7, k = i & 127;
        Wt[i] = f2bf(W[k * OUT_F + c]);
    }
}

// ===========================================================================
// Kernel 1: support = bf16(input @ W) via MFMA (~11 us, near HBM-read floor).
// ===========================================================================
__global__ __launch_bounds__(256) void gemm_mfma(
    const float* __restrict__ in, const unsigned short* __restrict__ Wt,
    unsigned short* __restrict__ support)
{
    __shared__ unsigned short Dl[64 * 68];     // 17 KB
    const int t    = threadIdx.x;
    const int lane = t & 63;
    const int rw   = t >> 6;                   // wave id 0..3
    const long rowB = (long)blockIdx.x * 64;
    const long row0 = rowB + rw * 16;

    const int lr = lane & 15;                  // A-row / B-col within tile
    const int lk = lane >> 4;                  // k-group (8 k each)

    long arow = row0 + lr;
    if (arow >= N_NODES) arow = N_NODES - 1;   // clamp (stores guarded)
    const float* Ap = in + arow * IN_F + lk * 8;
    const unsigned short* Wp = Wt + lk * 8;

    f32x4 acc0 = {0.f, 0.f, 0.f, 0.f};
    f32x4 acc1 = {0.f, 0.f, 0.f, 0.f};
    f32x4 acc2 = {0.f, 0.f, 0.f, 0.f};
    f32x4 acc3 = {0.f, 0.f, 0.f, 0.f};

    #pragma unroll
    for (int ks = 0; ks < 4; ++ks) {
        const float4 a01 = *(const float4*)(Ap + ks * 32);
        const float4 a23 = *(const float4*)(Ap + ks * 32 + 4);
        bf16x8 af;
        af[0] = (short)f2bf(a01.x); af[1] = (short)f2bf(a01.y);
        af[2] = (short)f2bf(a01.z); af[3] = (short)f2bf(a01.w);
        af[4] = (short)f2bf(a23.x); af[5] = (short)f2bf(a23.y);
        af[6] = (short)f2bf(a23.z); af[7] = (short)f2bf(a23.w);

        const int koff = ks * 32;
        bf16x8 b0 = *(const bf16x8*)(Wp + (0 * 16 + lr) * IN_F + koff);
        bf16x8 b1 = *(const bf16x8*)(Wp + (1 * 16 + lr) * IN_F + koff);
        bf16x8 b2 = *(const bf16x8*)(Wp + (2 * 16 + lr) * IN_F + koff);
        bf16x8 b3 = *(const bf16x8*)(Wp + (3 * 16 + lr) * IN_F + koff);

        acc0 = __builtin_amdgcn_mfma_f32_16x16x32_bf16(af, b0, acc0, 0, 0, 0);
        acc1 = __builtin_amdgcn_mfma_f32_16x16x32_bf16(af, b1, acc1, 0, 0, 0);
        acc2 = __builtin_amdgcn_mfma_f32_16x16x32_bf16(af, b2, acc2, 0, 0, 0);
        acc3 = __builtin_amdgcn_mfma_f32_16x16x32_bf16(af, b3, acc3, 0, 0, 0);
    }

    const int lrow = rw * 16 + lk * 4;
    #pragma unroll
    for (int r = 0; r < 4; ++r) {
        unsigned short* dst = Dl + (lrow + r) * 68;
        dst[ 0 + lr] = f2bf(acc0[r]);
        dst[16 + lr] = f2bf(acc1[r]);
        dst[32 + lr] = f2bf(acc2[r]);
        dst[48 + lr] = f2bf(acc3[r]);
    }
    __syncthreads();

    #pragma unroll
    for (int i = 0; i < 4; ++i) {
        const int idx = t + i * 256;
        const int row = idx >> 4;
        const int c2  = idx & 15;
        const long orow = rowB + row;
        if (orow < N_NODES) {
            const uint2 v = *(const uint2*)(Dl + row * 68 + c2 * 4);
            *(uint2*)(support + orow * OUT_F + c2 * 4) = v;
        }
    }
}

// ===========================================================================
// B3: LDS-hist bin, 1024 thr/block, 8-way sub-cursors (r18 structure).
// payload: x = (row&63)<<17 | col (col < 2^17), y = bits of val.
// ===========================================================================
__global__ __launch_bounds__(1024, 2) void bin_kernel(
    const int* __restrict__ rows, const int* __restrict__ cols,
    const float* __restrict__ vals, int* __restrict__ cursor,
    int* __restrict__ ovCount, uint4* __restrict__ ovList,
    uint2* __restrict__ binned, int nE)
{
    __shared__ int hist[NB];
    __shared__ int lbase[NB];
    const int t  = threadIdx.x;
    const int tb = blockIdx.x * BIN_TILE;
    const int g  = blockIdx.x & (NSEG - 1);

    for (int i = t; i < NB; i += 1024) hist[i] = 0;
    __syncthreads();

    int myr[4], myrank[4];
    #pragma unroll
    for (int i = 0; i < 4; ++i) {
        int e = tb + i * 1024 + t;
        if (e < nE) {
            int r = rows[e];
            myr[i] = r;
            myrank[i] = atomicAdd(&hist[r >> 6], 1);
        } else myr[i] = -1;
    }
    __syncthreads();

    for (int i = t; i < NB; i += 1024) {
        int h = hist[i];
        lbase[i] = h ? atomicAdd(&cursor[i * NSEG + g], h) : 0;
    }
    __syncthreads();

    #pragma unroll
    for (int i = 0; i < 4; ++i) {
        int e = tb + i * 1024 + t;
        if (e < nE) {
            const int r = myr[i];
            const int b = r >> 6;
            const int off = lbase[b] + myrank[i];
            if (off < SCAP) {
                unsigned pack = ((unsigned)(r & (BROWS - 1)) << 17)
                              | (unsigned)cols[e];
                binned[(size_t)b * BCAP + g * SCAP + off] =
                    make_uint2(pack, __float_as_uint(vals[e]));
            } else {
                int op = atomicAdd(ovCount, 1);
                if (op < OVCAP)
                    ovList[op] = make_uint4((unsigned)r, (unsigned)cols[e],
                                            __float_as_uint(vals[e]), 0u);
            }
        }
    }
}

// ===========================================================================
// B4 (no-sort accumulate, csr_spmm-style MLP): one block (1024 thr) / bucket.
// Stage+compact metadata in LDS (r18 flat staging), NO row-sort. Each wave:
// 8 broadcast LDS metadata reads -> 8 INDEPENDENT per-lane gathers (the
// exact idiom that measured 2.1 TB/s in csr_spmm) -> 8 ds_add_f32 into
// acc[row*64+lane] (2 lanes/bank = free). Tail: zero-val dummy (adds 0.0).
// r19 lesson: readlane-broadcast serializes (VGPR=8, 590us); per-lane
// unrolled gathers are mandatory.
// ===========================================================================
__global__ __launch_bounds__(1024, 2) void bucket_nosort(
    const int* __restrict__ cursor, const uint2* __restrict__ binned,
    const unsigned short* __restrict__ support, const float* __restrict__ bias,
    float* __restrict__ out)
{
    __shared__ float acc[BROWS * OUT_F];   // 16 KB
    __shared__ uint2 stage[CSB_CAP];       // 12.3 KB
    __shared__ int scnt[NSEG], soff[NSEG + 1];
    const int t = threadIdx.x;
    const int b = blockIdx.x;
    const size_t s = (size_t)b * BCAP;
    const int wid  = t >> 6;      // 0..15
    const int lane = t & 63;

    ((float4*)acc)[t] = make_float4(0.f, 0.f, 0.f, 0.f);
    if (t < NSEG) scnt[t] = min(cursor[b * NSEG + t], SCAP);
    __syncthreads();
    if (t == 0) {
        int run = 0;
        #pragma unroll
        for (int k = 0; k < NSEG; ++k) { soff[k] = run; run += scnt[k]; }
        soff[NSEG] = run;
    }
    __syncthreads();
    const int n = soff[NSEG];

    // flat predicated staging (compact): slot i -> seg i/SCAP, pos i%SCAP
    #pragma unroll
    for (int ii = 0; ii < (BCAP + 1023) / 1024; ++ii) {
        const int i = t + ii * 1024;
        if (i < BCAP) {
            const int seg = i / SCAP;
            const int pos = i - seg * SCAP;
            if (pos < scnt[seg])
                stage[soff[seg] + pos] = binned[s + i];
        }
    }
    __syncthreads();

    // 8-deep unrolled gather+LDS-atomic accumulate (per-lane addresses)
    const uint2 zed = make_uint2(0u, 0u);
    for (int j = wid * 8; j < n; j += 16 * 8) {
        uint2 q0 = (j + 0 < n) ? stage[j + 0] : zed;
        uint2 q1 = (j + 1 < n) ? stage[j + 1] : zed;
        uint2 q2 = (j + 2 < n) ? stage[j + 2] : zed;
        uint2 q3 = (j + 3 < n) ? stage[j + 3] : zed;
        uint2 q4 = (j + 4 < n) ? stage[j + 4] : zed;
        uint2 q5 = (j + 5 < n) ? stage[j + 5] : zed;
        uint2 q6 = (j + 6 < n) ? stage[j + 6] : zed;
        uint2 q7 = (j + 7 < n) ? stage[j + 7] : zed;
        float g0 = bf2f(support[((size_t)(q0.x & 131071u) << 6) + lane]);
        float g1 = bf2f(support[((size_t)(q1.x & 131071u) << 6) + lane]);
        float g2 = bf2f(support[((size_t)(q2.x & 131071u) << 6) + lane]);
        float g3 = bf2f(support[((size_t)(q3.x & 131071u) << 6) + lane]);
        float g4 = bf2f(support[((size_t)(q4.x & 131071u) << 6) + lane]);
        float g5 = bf2f(support[((size_t)(q5.x & 131071u) << 6) + lane]);
        float g6 = bf2f(support[((size_t)(q6.x & 131071u) << 6) + lane]);
        float g7 = bf2f(support[((size_t)(q7.x & 131071u) << 6) + lane]);
        atomicAdd(&acc[((q0.x >> 17) << 6) + lane], __uint_as_float(q0.y) * g0);
        atomicAdd(&acc[((q1.x >> 17) << 6) + lane], __uint_as_float(q1.y) * g1);
        atomicAdd(&acc[((q2.x >> 17) << 6) + lane], __uint_as_float(q2.y) * g2);
        atomicAdd(&acc[((q3.x >> 17) << 6) + lane], __uint_as_float(q3.y) * g3);
        atomicAdd(&acc[((q4.x >> 17) << 6) + lane], __uint_as_float(q4.y) * g4);
        atomicAdd(&acc[((q5.x >> 17) << 6) + lane], __uint_as_float(q5.y) * g5);
        atomicAdd(&acc[((q6.x >> 17) << 6) + lane], __uint_as_float(q6.y) * g6);
        atomicAdd(&acc[((q7.x >> 17) << 6) + lane], __uint_as_float(q7.y) * g7);
    }
    __syncthreads();

    // epilogue: out = acc + bias (coalesced, 4 rows/wave)
    const int row0 = b * BROWS;
    const float bv = bias[lane];
    #pragma unroll
    for (int q = 0; q < 4; ++q) {
        const int rr = wid * 4 + q;
        const int r  = row0 + rr;
        if (r < N_NODES)
            out[(size_t)r * OUT_F + lane] = acc[(rr << 6) + lane] + bv;
    }
}

// ===========================================================================
// B5: overflow fixup (normally 0 edges -> ~no-op). One wave per edge.
// ===========================================================================
__global__ __launch_bounds__(256) void ovfix_kernel(
    const int* __restrict__ ovCount, const uint4* __restrict__ ovList,
    const unsigned short* __restrict__ support, float* __restrict__ out)
{
    const int n = min(*ovCount, OVCAP);
    const int lane = threadIdx.x & 63;
    for (int e = blockIdx.x * 4 + (threadIdx.x >> 6); e < n; e += 32 * 4) {
        const uint4 p = ovList[e];
        const float m = __uint_as_float(p.z) *
                        bf2f(support[((size_t)p.y << 6) + lane]);
        atomicAdd(&out[((size_t)p.x << 6) + lane], m);
    }
}

// ===========================================================================
// Fallback path (ws too small): VALU gemm + bias-init + atomic scatter
// ===========================================================================
__global__ __launch_bounds__(256) void gemm_valu(
    const float* __restrict__ in, const float* __restrict__ W,
    unsigned short* __restrict__ support)
{
    __shared__ float Alds[64 * IN_F];
    const int t = threadIdx.x;
    const long row0 = (long)blockIdx.x * 64;
    #pragma unroll
    for (int i = 0; i < 8; ++i) {
        int fi = t + i * 256;
        int r  = fi >> 5;
        int c4 = (fi & 31) << 2;
        float4 v = make_float4(0.f, 0.f, 0.f, 0.f);
        if (row0 + r < N_NODES)
            v = *(const float4*)(in + (row0 + r) * IN_F + c4);
        *(float4*)(Alds + r * IN_F + c4) = v;
    }
    __syncthreads();
    const int lane = t & 63;
    const int c0   = __builtin_amdgcn_readfirstlane((t >> 6) << 4);
    const float* __restrict__ Wp = W + c0;
    float acc[16];
    #pragma unroll
    for (int i = 0; i < 16; ++i) acc[i] = 0.f;
    const float* Ar = Alds + lane * IN_F;
    for (int k = 0; k < IN_F; ++k) {
        const float a = Ar[k];
        const float4 w0 = *(const float4*)(Wp + k * OUT_F + 0);
        const float4 w1 = *(const float4*)(Wp + k * OUT_F + 4);
        const float4 w2 = *(const float4*)(Wp + k * OUT_F + 8);
        const float4 w3 = *(const float4*)(Wp + k * OUT_F + 12);
        acc[0]  = fmaf(a, w0.x, acc[0]);  acc[1]  = fmaf(a, w0.y, acc[1]);
        acc[2]  = fmaf(a, w0.z, acc[2]);  acc[3]  = fmaf(a, w0.w, acc[3]);
        acc[4]  = fmaf(a, w1.x, acc[4]);  acc[5]  = fmaf(a, w1.y, acc[5]);
        acc[6]  = fmaf(a, w1.z, acc[6]);  acc[7]  = fmaf(a, w1.w, acc[7]);
        acc[8]  = fmaf(a, w2.x, acc[8]);  acc[9]  = fmaf(a, w2.y, acc[9]);
        acc[10] = fmaf(a, w2.z, acc[10]); acc[11] = fmaf(a, w2.w, acc[11]);
        acc[12] = fmaf(a, w3.x, acc[12]); acc[13] = fmaf(a, w3.y, acc[13]);
        acc[14] = fmaf(a, w3.z, acc[14]); acc[15] = fmaf(a, w3.w, acc[15]);
    }
    const long orow = row0 + lane;
    if (orow < N_NODES) {
        unsigned short* o = support + orow * OUT_F + c0;
        #pragma unroll
        for (int i = 0; i < 16; ++i) o[i] = f2bf(acc[i]);
    }
}

__global__ __launch_bounds__(256) void bias_init_kernel(
    float* __restrict__ out, const float* __restrict__ bias, int total4)
{
    const float4* b4 = (const float4*)bias;
    float4* o4 = (float4*)out;
    int i = blockIdx.x * blockDim.x + threadIdx.x;
    int stride = gridDim.x * blockDim.x;
    for (; i < total4; i += stride)
        o4[i] = b4[i & 15];
}

__global__ __launch_bounds__(256) void scatter_kernel(
    const float* __restrict__ vals, const int* __restrict__ rows,
    const int* __restrict__ cols, const unsigned short* __restrict__ support,
    float* __restrict__ out, int nE)
{
    const int e = blockIdx.x * 4 + (threadIdx.x >> 6);
    if (e >= nE) return;
    const int f = threadIdx.x & 63;
    const float m = vals[e] * bf2f(support[(size_t)cols[e] * OUT_F + f]);
    atomicAdd(&out[(size_t)rows[e] * OUT_F + f], m);
}

// ===========================================================================
extern "C" void kernel_launch(void* const* d_in, const int* in_sizes, int n_in,
                              void* d_out, int out_size, void* d_ws, size_t ws_size,
                              hipStream_t stream) {
    const float* input    = (const float*)d_in[0];
    const float* weights  = (const float*)d_in[1];
    const float* bias     = (const float*)d_in[2];
    const float* adj_vals = (const float*)d_in[3];
    const int*   adj_rows = (const int*)d_in[4];
    const int*   adj_cols = (const int*)d_in[5];
    const int nE = in_sizes[3];

    float* out = (float*)d_out;
    const int gemmBlocks = (N_NODES + 63) / 64;            // 1563
    const int binBlocks  = (nE + BIN_TILE - 1) / BIN_TILE; // 391

    // workspace layout (16B-aligned offsets)
    char* ws = (char*)d_ws;
    const size_t off_support = 0;                           // 12.8 MB
    const size_t off_wt      = 12800000;                    // 16 KB
    const size_t off_cursor  = off_wt + 16384;              // NB*NSEG+1 ints
    const size_t off_binned  = off_cursor + 51200;          // NB*BCAP uint2 ~19.2MB
    const size_t off_ovlist  = off_binned + (size_t)NB * BCAP * 8;
    const size_t required    = off_ovlist + (size_t)OVCAP * 16;   // ~34.2 MB

    unsigned short* support = (unsigned short*)(ws + off_support);
    unsigned short* Wt      = (unsigned short*)(ws + off_wt);
    int*   cursor  = (int*)  (ws + off_cursor);      // [NB*NSEG], then ovCount
    uint2* binned  = (uint2*)(ws + off_binned);
    uint4* ovList  = (uint4*)(ws + off_ovlist);
    int*   ovCount = cursor + NB * NSEG;

    if (ws_size >= required) {
        // 1) sub-cursors + ovCount = 0
        hipMemsetAsync(cursor, 0, (NB * NSEG + 1) * sizeof(int), stream);
        // 2) Wt = bf16(W^T)
        hipLaunchKernelGGL(wt_kernel, dim3(32), dim3(256), 0, stream,
                           weights, Wt);
        // 3) support = bf16(input @ W)  (MFMA, LDS-coalesced epilogue)
        hipLaunchKernelGGL(gemm_mfma, dim3(gemmBlocks), dim3(256), 0, stream,
                           input, Wt, support);
        // 4) bin edges (LDS hist, 16 waves/block, 8-way sub-cursors)
        hipLaunchKernelGGL(bin_kernel, dim3(binBlocks), dim3(1024), 0, stream,
                           adj_rows, adj_cols, adj_vals, cursor,
                           ovCount, ovList, binned, nE);
        // 5) per-bucket no-sort LDS accumulate + bias -> out
        hipLaunchKernelGGL(bucket_nosort, dim3(NB), dim3(1024), 0, stream,
                           cursor, binned, support, bias, out);
        // 6) overflow fixup (no-op unless a segment exceeded SCAP)
        hipLaunchKernelGGL(ovfix_kernel, dim3(32), dim3(256), 0, stream,
                           ovCount, ovList, support, out);
    } else {
        // minimal-workspace fallback (VALU gemm, then atomic scatter)
        hipLaunchKernelGGL(gemm_valu, dim3(gemmBlocks), dim3(256), 0, stream,
                           input, weights, support);
        hipLaunchKernelGGL(bias_init_kernel, dim3(2048), dim3(256), 0, stream,
                           out, bias, N_NODES * OUT_F / 4);
        hipLaunchKernelGGL(scatter_kernel, dim3((nE + 3) / 4), dim3(256),
                           0, stream, adj_vals, adj_rows, adj_cols, support,
                           out, nE);
    }
}

// Round 21
// 116.197 us; speedup vs baseline: 5.7808x; 5.7808x over previous
//
#include <hip/hip_runtime.h>
#include <hip/hip_bf16.h>

#define N_NODES 100000
#define IN_F 128
#define OUT_F 64
#define BROWS 64                  // rows per bucket
#define NB 1563                   // ceil(100000/64)
#define BIN_TILE 4096             // edges per bin tile
#define NSEG 4                    // sub-cursors per bucket
#define SCAP 352                  // segment capacity (mean 256 + 6 sigma)
#define BCAP (NSEG * SCAP)        // 1408 per bucket
#define OVCAP 131072              // overflow list capacity
#define CSB_CAP BCAP              // csr_spmm LDS edge buffers

typedef __attribute__((ext_vector_type(8))) short bf16x8;
typedef __attribute__((ext_vector_type(4))) float f32x4;

// RNE float -> bf16 (bits)
__device__ __forceinline__ unsigned short f2bf(float x) {
    unsigned u = __float_as_uint(x);
    u += 0x7FFFu + ((u >> 16) & 1u);
    return (unsigned short)(u >> 16);
}
// bf16 (bits) -> float (exact)
__device__ __forceinline__ float bf2f(unsigned short s) {
    return __uint_as_float(((unsigned)s) << 16);
}

// ===========================================================================
// Kernel 0: Wt[c][k] = bf16(W[k][c])  (64 x 128 bf16, 16 KB, L2-hot after)
// ===========================================================================
__global__ __launch_bounds__(256) void wt_kernel(
    const float* __restrict__ W, unsigned short* __restrict__ Wt)
{
    int i = blockIdx.x * 256 + threadIdx.x;
    if (i < IN_F * OUT_F) {
        int c = i >> 7, k = i & 127;
        Wt[i] = f2bf(W[k * OUT_F + c]);
    }
}

// ===========================================================================
// Kernel 1: support = bf16(input @ W) via MFMA (~11 us, near HBM-read floor).
// ===========================================================================
__global__ __launch_bounds__(256) void gemm_mfma(
    const float* __restrict__ in, const unsigned short* __restrict__ Wt,
    unsigned short* __restrict__ support)
{
    __shared__ unsigned short Dl[64 * 68];     // 17 KB
    const int t    = threadIdx.x;
    const int lane = t & 63;
    const int rw   = t >> 6;                   // wave id 0..3
    const long rowB = (long)blockIdx.x * 64;
    const long row0 = rowB + rw * 16;

    const int lr = lane & 15;                  // A-row / B-col within tile
    const int lk = lane >> 4;                  // k-group (8 k each)

    long arow = row0 + lr;
    if (arow >= N_NODES) arow = N_NODES - 1;   // clamp (stores guarded)
    const float* Ap = in + arow * IN_F + lk * 8;
    const unsigned short* Wp = Wt + lk * 8;

    f32x4 acc0 = {0.f, 0.f, 0.f, 0.f};
    f32x4 acc1 = {0.f, 0.f, 0.f, 0.f};
    f32x4 acc2 = {0.f, 0.f, 0.f, 0.f};
    f32x4 acc3 = {0.f, 0.f, 0.f, 0.f};

    #pragma unroll
    for (int ks = 0; ks < 4; ++ks) {
        const float4 a01 = *(const float4*)(Ap + ks * 32);
        const float4 a23 = *(const float4*)(Ap + ks * 32 + 4);
        bf16x8 af;
        af[0] = (short)f2bf(a01.x); af[1] = (short)f2bf(a01.y);
        af[2] = (short)f2bf(a01.z); af[3] = (short)f2bf(a01.w);
        af[4] = (short)f2bf(a23.x); af[5] = (short)f2bf(a23.y);
        af[6] = (short)f2bf(a23.z); af[7] = (short)f2bf(a23.w);

        const int koff = ks * 32;
        bf16x8 b0 = *(const bf16x8*)(Wp + (0 * 16 + lr) * IN_F + koff);
        bf16x8 b1 = *(const bf16x8*)(Wp + (1 * 16 + lr) * IN_F + koff);
        bf16x8 b2 = *(const bf16x8*)(Wp + (2 * 16 + lr) * IN_F + koff);
        bf16x8 b3 = *(const bf16x8*)(Wp + (3 * 16 + lr) * IN_F + koff);

        acc0 = __builtin_amdgcn_mfma_f32_16x16x32_bf16(af, b0, acc0, 0, 0, 0);
        acc1 = __builtin_amdgcn_mfma_f32_16x16x32_bf16(af, b1, acc1, 0, 0, 0);
        acc2 = __builtin_amdgcn_mfma_f32_16x16x32_bf16(af, b2, acc2, 0, 0, 0);
        acc3 = __builtin_amdgcn_mfma_f32_16x16x32_bf16(af, b3, acc3, 0, 0, 0);
    }

    const int lrow = rw * 16 + lk * 4;
    #pragma unroll
    for (int r = 0; r < 4; ++r) {
        unsigned short* dst = Dl + (lrow + r) * 68;
        dst[ 0 + lr] = f2bf(acc0[r]);
        dst[16 + lr] = f2bf(acc1[r]);
        dst[32 + lr] = f2bf(acc2[r]);
        dst[48 + lr] = f2bf(acc3[r]);
    }
    __syncthreads();

    #pragma unroll
    for (int i = 0; i < 4; ++i) {
        const int idx = t + i * 256;
        const int row = idx >> 4;
        const int c2  = idx & 15;
        const long orow = rowB + row;
        if (orow < N_NODES) {
            const uint2 v = *(const uint2*)(Dl + row * 68 + c2 * 4);
            *(uint2*)(support + orow * OUT_F + c2 * 4) = v;
        }
    }
}

// ===========================================================================
// B3: LDS-hist bin, 1024 thr/block, 4-way sub-cursors.
// payload: x = (row&63)<<17 | col (col < 2^17), y = bits of val.
// ===========================================================================
__global__ __launch_bounds__(1024, 2) void bin_kernel(
    const int* __restrict__ rows, const int* __restrict__ cols,
    const float* __restrict__ vals, int* __restrict__ cursor,
    int* __restrict__ ovCount, uint4* __restrict__ ovList,
    uint2* __restrict__ binned, int nE)
{
    __shared__ int hist[NB];
    __shared__ int lbase[NB];
    const int t  = threadIdx.x;
    const int tb = blockIdx.x * BIN_TILE;
    const int g  = blockIdx.x & (NSEG - 1);

    for (int i = t; i < NB; i += 1024) hist[i] = 0;
    __syncthreads();

    int myr[4], myrank[4];
    #pragma unroll
    for (int i = 0; i < 4; ++i) {
        int e = tb + i * 1024 + t;
        if (e < nE) {
            int r = rows[e];
            myr[i] = r;
            myrank[i] = atomicAdd(&hist[r >> 6], 1);
        } else myr[i] = -1;
    }
    __syncthreads();

    for (int i = t; i < NB; i += 1024) {
        int h = hist[i];
        lbase[i] = h ? atomicAdd(&cursor[i * NSEG + g], h) : 0;
    }
    __syncthreads();

    #pragma unroll
    for (int i = 0; i < 4; ++i) {
        int e = tb + i * 1024 + t;
        if (e < nE) {
            const int r = myr[i];
            const int b = r >> 6;
            const int off = lbase[b] + myrank[i];
            if (off < SCAP) {
                unsigned pack = ((unsigned)(r & (BROWS - 1)) << 17)
                              | (unsigned)cols[e];
                binned[(size_t)b * BCAP + g * SCAP + off] =
                    make_uint2(pack, __float_as_uint(vals[e]));
            } else {
                int op = atomicAdd(ovCount, 1);
                if (op < OVCAP)
                    ovList[op] = make_uint4((unsigned)r, (unsigned)cols[e],
                                            __float_as_uint(vals[e]), 0u);
            }
        }
    }
}

// ===========================================================================
// B4 (fused csr+spmm): one block (1024 thr = 16 waves) per bucket.
// Stage the bucket's 4 segments back-to-back in LDS, row-sort, then
// 16 waves x 4 rows: per-row gather (8 independent gathers in flight,
// register-fmaf consumer -- the shape that preserves MLP), bias fused.
// ===========================================================================
__global__ __launch_bounds__(1024, 2) void csr_spmm(
    const int* __restrict__ cursor, const uint2* __restrict__ binned,
    const unsigned short* __restrict__ support, const float* __restrict__ bias,
    float* __restrict__ out)
{
    __shared__ uint2 stage[CSB_CAP];     // 11 KB
    __shared__ uint2 sorted[CSB_CAP];    // 11 KB
    __shared__ int rh[BROWS], rs[BROWS + 1], rc[BROWS];
    const int t = threadIdx.x;
    const int b = blockIdx.x;
    const size_t s = (size_t)b * BCAP;
    const int wid  = t >> 6;      // 0..15
    const int lane = t & 63;
    const int row0 = b * BROWS;

    const int n0 = min(cursor[b * NSEG + 0], SCAP);
    const int n1 = min(cursor[b * NSEG + 1], SCAP);
    const int n2 = min(cursor[b * NSEG + 2], SCAP);
    const int n3 = min(cursor[b * NSEG + 3], SCAP);
    const int o1 = n0, o2 = n0 + n1, o3 = o2 + n2;
    const int n  = o3 + n3;

    if (t < BROWS) rh[t] = 0;
    __syncthreads();

    for (int i = t; i < n0; i += 1024) {
        uint2 p = binned[s + 0 * SCAP + i];
        stage[i] = p;           atomicAdd(&rh[p.x >> 17], 1);
    }
    for (int i = t; i < n1; i += 1024) {
        uint2 p = binned[s + 1 * SCAP + i];
        stage[o1 + i] = p;      atomicAdd(&rh[p.x >> 17], 1);
    }
    for (int i = t; i < n2; i += 1024) {
        uint2 p = binned[s + 2 * SCAP + i];
        stage[o2 + i] = p;      atomicAdd(&rh[p.x >> 17], 1);
    }
    for (int i = t; i < n3; i += 1024) {
        uint2 p = binned[s + 3 * SCAP + i];
        stage[o3 + i] = p;      atomicAdd(&rh[p.x >> 17], 1);
    }
    __syncthreads();

    if (t < BROWS) {
        int v = rh[t];
        int inc = v;
        #pragma unroll
        for (int off = 1; off < BROWS; off <<= 1) {
            int y = __shfl_up(inc, off, 64);
            if (t >= off) inc += y;
        }
        rs[t] = inc - v;
        rc[t] = inc - v;
        if (t == BROWS - 1) rs[BROWS] = inc;
    }
    __syncthreads();
    for (int i = t; i < n; i += 1024) {
        uint2 p = stage[i];
        int pos = atomicAdd(&rc[p.x >> 17], 1);
        sorted[pos] = p;
    }
    __syncthreads();

    #pragma unroll
    for (int q = 0; q < 4; ++q) {
        const int rr = wid * 4 + q;
        const int r  = row0 + rr;
        if (r >= N_NODES) break;
        float acc = bias[lane];
        int j  = rs[rr];
        const int je = rs[rr + 1];
        for (; j + 7 < je; j += 8) {
            uint2 q0 = sorted[j + 0];
            uint2 q1 = sorted[j + 1];
            uint2 q2 = sorted[j + 2];
            uint2 q3 = sorted[j + 3];
            uint2 q4 = sorted[j + 4];
            uint2 q5 = sorted[j + 5];
            uint2 q6 = sorted[j + 6];
            uint2 q7 = sorted[j + 7];
            float g0 = bf2f(support[((size_t)(q0.x & 131071u) << 6) + lane]);
            float g1 = bf2f(support[((size_t)(q1.x & 131071u) << 6) + lane]);
            float g2 = bf2f(support[((size_t)(q2.x & 131071u) << 6) + lane]);
            float g3 = bf2f(support[((size_t)(q3.x & 131071u) << 6) + lane]);
            float g4 = bf2f(support[((size_t)(q4.x & 131071u) << 6) + lane]);
            float g5 = bf2f(support[((size_t)(q5.x & 131071u) << 6) + lane]);
            float g6 = bf2f(support[((size_t)(q6.x & 131071u) << 6) + lane]);
            float g7 = bf2f(support[((size_t)(q7.x & 131071u) << 6) + lane]);
            acc = fmaf(__uint_as_float(q0.y), g0, acc);
            acc = fmaf(__uint_as_float(q1.y), g1, acc);
            acc = fmaf(__uint_as_float(q2.y), g2, acc);
            acc = fmaf(__uint_as_float(q3.y), g3, acc);
            acc = fmaf(__uint_as_float(q4.y), g4, acc);
            acc = fmaf(__uint_as_float(q5.y), g5, acc);
            acc = fmaf(__uint_as_float(q6.y), g6, acc);
            acc = fmaf(__uint_as_float(q7.y), g7, acc);
        }
        for (; j < je; ++j) {
            uint2 p = sorted[j];
            acc = fmaf(__uint_as_float(p.y),
                       bf2f(support[((size_t)(p.x & 131071u) << 6) + lane]),
                       acc);
        }
        out[(size_t)r * OUT_F + lane] = acc;
    }
}

// ===========================================================================
// B5: overflow fixup (normally 0 edges -> ~no-op). One wave per edge.
// ===========================================================================
__global__ __launch_bounds__(256) void ovfix_kernel(
    const int* __restrict__ ovCount, const uint4* __restrict__ ovList,
    const unsigned short* __restrict__ support, float* __restrict__ out)
{
    const int n = min(*ovCount, OVCAP);
    const int lane = threadIdx.x & 63;
    for (int e = blockIdx.x * 4 + (threadIdx.x >> 6); e < n; e += 32 * 4) {
        const uint4 p = ovList[e];
        const float m = __uint_as_float(p.z) *
                        bf2f(support[((size_t)p.y << 6) + lane]);
        atomicAdd(&out[((size_t)p.x << 6) + lane], m);
    }
}

// ===========================================================================
// Fallback path (ws too small): VALU gemm + bias-init + atomic scatter
// ===========================================================================
__global__ __launch_bounds__(256) void gemm_valu(
    const float* __restrict__ in, const float* __restrict__ W,
    unsigned short* __restrict__ support)
{
    __shared__ float Alds[64 * IN_F];
    const int t = threadIdx.x;
    const long row0 = (long)blockIdx.x * 64;
    #pragma unroll
    for (int i = 0; i < 8; ++i) {
        int fi = t + i * 256;
        int r  = fi >> 5;
        int c4 = (fi & 31) << 2;
        float4 v = make_float4(0.f, 0.f, 0.f, 0.f);
        if (row0 + r < N_NODES)
            v = *(const float4*)(in + (row0 + r) * IN_F + c4);
        *(float4*)(Alds + r * IN_F + c4) = v;
    }
    __syncthreads();
    const int lane = t & 63;
    const int c0   = __builtin_amdgcn_readfirstlane((t >> 6) << 4);
    const float* __restrict__ Wp = W + c0;
    float acc[16];
    #pragma unroll
    for (int i = 0; i < 16; ++i) acc[i] = 0.f;
    const float* Ar = Alds + lane * IN_F;
    for (int k = 0; k < IN_F; ++k) {
        const float a = Ar[k];
        const float4 w0 = *(const float4*)(Wp + k * OUT_F + 0);
        const float4 w1 = *(const float4*)(Wp + k * OUT_F + 4);
        const float4 w2 = *(const float4*)(Wp + k * OUT_F + 8);
        const float4 w3 = *(const float4*)(Wp + k * OUT_F + 12);
        acc[0]  = fmaf(a, w0.x, acc[0]);  acc[1]  = fmaf(a, w0.y, acc[1]);
        acc[2]  = fmaf(a, w0.z, acc[2]);  acc[3]  = fmaf(a, w0.w, acc[3]);
        acc[4]  = fmaf(a, w1.x, acc[4]);  acc[5]  = fmaf(a, w1.y, acc[5]);
        acc[6]  = fmaf(a, w1.z, acc[6]);  acc[7]  = fmaf(a, w1.w, acc[7]);
        acc[8]  = fmaf(a, w2.x, acc[8]);  acc[9]  = fmaf(a, w2.y, acc[9]);
        acc[10] = fmaf(a, w2.z, acc[10]); acc[11] = fmaf(a, w2.w, acc[11]);
        acc[12] = fmaf(a, w3.x, acc[12]); acc[13] = fmaf(a, w3.y, acc[13]);
        acc[14] = fmaf(a, w3.z, acc[14]); acc[15] = fmaf(a, w3.w, acc[15]);
    }
    const long orow = row0 + lane;
    if (orow < N_NODES) {
        unsigned short* o = support + orow * OUT_F + c0;
        #pragma unroll
        for (int i = 0; i < 16; ++i) o[i] = f2bf(acc[i]);
    }
}

__global__ __launch_bounds__(256) void bias_init_kernel(
    float* __restrict__ out, const float* __restrict__ bias, int total4)
{
    const float4* b4 = (const float4*)bias;
    float4* o4 = (float4*)out;
    int i = blockIdx.x * blockDim.x + threadIdx.x;
    int stride = gridDim.x * blockDim.x;
    for (; i < total4; i += stride)
        o4[i] = b4[i & 15];
}

__global__ __launch_bounds__(256) void scatter_kernel(
    const float* __restrict__ vals, const int* __restrict__ rows,
    const int* __restrict__ cols, const unsigned short* __restrict__ support,
    float* __restrict__ out, int nE)
{
    const int e = blockIdx.x * 4 + (threadIdx.x >> 6);
    if (e >= nE) return;
    const int f = threadIdx.x & 63;
    const float m = vals[e] * bf2f(support[(size_t)cols[e] * OUT_F + f]);
    atomicAdd(&out[(size_t)rows[e] * OUT_F + f], m);
}

// ===========================================================================
extern "C" void kernel_launch(void* const* d_in, const int* in_sizes, int n_in,
                              void* d_out, int out_size, void* d_ws, size_t ws_size,
                              hipStream_t stream) {
    const float* input    = (const float*)d_in[0];
    const float* weights  = (const float*)d_in[1];
    const float* bias     = (const float*)d_in[2];
    const float* adj_vals = (const float*)d_in[3];
    const int*   adj_rows = (const int*)d_in[4];
    const int*   adj_cols = (const int*)d_in[5];
    const int nE = in_sizes[3];

    float* out = (float*)d_out;
    const int gemmBlocks = (N_NODES + 63) / 64;            // 1563
    const int binBlocks  = (nE + BIN_TILE - 1) / BIN_TILE; // 391

    // workspace layout (16B-aligned offsets)
    char* ws = (char*)d_ws;
    const size_t off_support = 0;                           // 12.8 MB
    const size_t off_wt      = 12800000;                    // 16 KB
    const size_t off_cursor  = off_wt + 16384;              // NB*NSEG+1 ints
    const size_t off_binned  = off_cursor + 25600;          // NB*BCAP uint2 ~17.6MB
    const size_t off_ovlist  = off_binned + (size_t)NB * BCAP * 8;
    const size_t required    = off_ovlist + (size_t)OVCAP * 16;

    unsigned short* support = (unsigned short*)(ws + off_support);
    unsigned short* Wt      = (unsigned short*)(ws + off_wt);
    int*   cursor  = (int*)  (ws + off_cursor);      // [NB*NSEG], then ovCount
    uint2* binned  = (uint2*)(ws + off_binned);
    uint4* ovList  = (uint4*)(ws + off_ovlist);
    int*   ovCount = cursor + NB * NSEG;

    if (ws_size >= required) {
        // 1) sub-cursors + ovCount = 0
        hipMemsetAsync(cursor, 0, (NB * NSEG + 1) * sizeof(int), stream);
        // 2) Wt = bf16(W^T)
        hipLaunchKernelGGL(wt_kernel, dim3(32), dim3(256), 0, stream,
                           weights, Wt);
        // 3) support = bf16(input @ W)  (MFMA, LDS-coalesced epilogue)
        hipLaunchKernelGGL(gemm_mfma, dim3(gemmBlocks), dim3(256), 0, stream,
                           input, Wt, support);
        // 4) bin edges (LDS hist, 16 waves/block, 4-way sub-cursors)
        hipLaunchKernelGGL(bin_kernel, dim3(binBlocks), dim3(1024), 0, stream,
                           adj_rows, adj_cols, adj_vals, cursor,
                           ovCount, ovList, binned, nE);
        // 5) fused per-bucket LDS row-sort + per-row wave gather + bias
        hipLaunchKernelGGL(csr_spmm, dim3(NB), dim3(1024), 0, stream,
                           cursor, binned, support, bias, out);
        // 6) overflow fixup (no-op unless a segment exceeded SCAP)
        hipLaunchKernelGGL(ovfix_kernel, dim3(32), dim3(256), 0, stream,
                           ovCount, ovList, support, out);
    } else {
        // minimal-workspace fallback (VALU gemm, then atomic scatter)
        hipLaunchKernelGGL(gemm_valu, dim3(gemmBlocks), dim3(256), 0, stream,
                           input, weights, support);
        hipLaunchKernelGGL(bias_init_kernel, dim3(2048), dim3(256), 0, stream,
                           out, bias, N_NODES * OUT_F / 4);
        hipLaunchKernelGGL(scatter_kernel, dim3((nE + 3) / 4), dim3(256),
                           0, stream, adj_vals, adj_rows, adj_cols, support,
                           out, nE);
    }
}